// Round 1
// baseline (1011.822 us; speedup 1.0000x reference)
//
#include <hip/hip_runtime.h>
#include <stdint.h>

// SimpleTrixFFN: soft-routed 8-tile FFN + classifier on MI355X.
// Strategy: fp32 routing (exact argmax), bf16 MFMA GEMMs (16x16x32) with
// fp32 accumulate, weight folded into h at up-GEMM epilogue, per-tile loop.

typedef __attribute__((ext_vector_type(8))) __bf16 bf16x8;
typedef __attribute__((ext_vector_type(4))) float f32x4;

__device__ __forceinline__ unsigned short f2bf(float f) {
  union { float f; unsigned int u; } c; c.f = f;
  unsigned int u = c.u;
  u += 0x7FFFu + ((u >> 16) & 1u);   // round-to-nearest-even
  return (unsigned short)(u >> 16);
}

__device__ __forceinline__ float gelu_exact(float v) {
  return 0.5f * v * (1.0f + erff(v * 0.70710678118654752440f));
}

__device__ __forceinline__ void gload16(const void* g, void* l) {
  __builtin_amdgcn_global_load_lds((const __attribute__((address_space(1))) void*)g,
                                   (__attribute__((address_space(3))) void*)l,
                                   16, 0, 0);
}

// ---------------- conversion kernels ----------------
__global__ void conv_bf16(const float* __restrict__ in, unsigned short* __restrict__ out, int n4) {
  int i = blockIdx.x * blockDim.x + threadIdx.x;
  if (i >= n4) return;
  float4 v = reinterpret_cast<const float4*>(in)[i];
  ushort4 o;
  o.x = f2bf(v.x); o.y = f2bf(v.y); o.z = f2bf(v.z); o.w = f2bf(v.w);
  reinterpret_cast<ushort4*>(out)[i] = o;
}

// W_cls (1000,1024) -> padded bf16 (1024,1024), zero rows 1000..1023
__global__ void conv_wcls(const float* __restrict__ in, unsigned short* __restrict__ out) {
  int i = blockIdx.x * blockDim.x + threadIdx.x;   // 262144 threads
  int idx = i * 4;
  int row = idx >> 10;
  float4 v = make_float4(0.f, 0.f, 0.f, 0.f);
  if (row < 1000) v = *reinterpret_cast<const float4*>(in + row * 1024 + (idx & 1023));
  ushort4 o;
  o.x = f2bf(v.x); o.y = f2bf(v.y); o.z = f2bf(v.z); o.w = f2bf(v.w);
  reinterpret_cast<ushort4*>(out)[i] = o;
}

// ---------------- routing: scores, softmax, argmax, out-init ----------------
// one block (256 thr) per batch row
__global__ void score_init(const float* __restrict__ x, const float* __restrict__ sig,
                           const float* __restrict__ b_down,
                           float* __restrict__ w_ws, float* __restrict__ out_init,
                           float* __restrict__ w_out, float* __restrict__ idx_out) {
  const int b = blockIdx.x;
  const int tid = threadIdx.x;
  const int lane = tid & 63;
  const int wave = tid >> 6;
  const float* xr = x + (size_t)b * 1024;

  float p[8];
  #pragma unroll
  for (int t = 0; t < 8; ++t) p[t] = 0.f;

  for (int k = tid; k < 1024; k += 256) {
    float xv = xr[k];
    #pragma unroll
    for (int t = 0; t < 8; ++t) p[t] += xv * sig[t * 1024 + k];
  }
  #pragma unroll
  for (int t = 0; t < 8; ++t) {
    #pragma unroll
    for (int off = 32; off > 0; off >>= 1) p[t] += __shfl_down(p[t], off);
  }
  __shared__ float red[4][8];
  __shared__ float wsh[8];
  if (lane == 0) {
    #pragma unroll
    for (int t = 0; t < 8; ++t) red[wave][t] = p[t];
  }
  __syncthreads();
  if (tid == 0) {
    float s[8];
    #pragma unroll
    for (int t = 0; t < 8; ++t) s[t] = red[0][t] + red[1][t] + red[2][t] + red[3][t];
    int amax = 0; float mx = s[0];
    #pragma unroll
    for (int t = 1; t < 8; ++t) { if (s[t] > mx) { mx = s[t]; amax = t; } }
    float e[8], sum = 0.f;
    #pragma unroll
    for (int t = 0; t < 8; ++t) { e[t] = expf((s[t] - mx) * 2.0f); sum += e[t]; }
    float inv = 1.0f / sum;
    #pragma unroll
    for (int t = 0; t < 8; ++t) {
      float wv = e[t] * inv;
      wsh[t] = wv;
      w_out[(size_t)b * 8 + t] = wv;
      w_ws[(size_t)b * 8 + t] = wv;
    }
    idx_out[b] = (float)amax;
  }
  __syncthreads();
  // out_init = x + sum_t w_t * b_down[t]
  for (int d = tid; d < 1024; d += 256) {
    float acc = xr[d];
    #pragma unroll
    for (int t = 0; t < 8; ++t) acc += wsh[t] * b_down[t * 1024 + d];
    out_init[(size_t)b * 1024 + d] = acc;
  }
}

// ---------------- GEMM: C[m][n] = sum_k A[m][k] * B[n][k]  (both bf16 row-major) ----------
// BM=128, BK=64.  EPI: 0 = up (gelu*w -> bf16 Ch), 1 = down (+= into Cf), 2 = cls (Cf = v + bias, guard n)
template <int BN, int EPI>
__global__ __launch_bounds__(256, 2) void gemm_k(
    const unsigned short* __restrict__ A, int lda,
    const unsigned short* __restrict__ Bm, int ldb,
    int K,
    float* __restrict__ Cf, int ldc, int nvalid,
    unsigned short* __restrict__ Ch, int ldh,
    const float* __restrict__ bias,
    const float* __restrict__ wcol) {
  constexpr int FN = BN / 32;        // fragments in N per wave
  constexpr int AISS = 4;            // 128 rows * 128B / (256 lanes * 16B)
  constexpr int BISS = BN / 32;

  __shared__ unsigned short As[128 * 64];
  __shared__ unsigned short Bs[BN * 64];

  const int tid  = threadIdx.x;
  const int lane = tid & 63;
  const int wave = tid >> 6;
  const int m0 = blockIdx.y * 128;
  const int n0 = blockIdx.x * BN;
  const int lr = lane & 15;
  const int lg = lane >> 4;
  const int wm = (wave >> 1) * 64;
  const int wn = (wave & 1) * (BN / 2);
  const int sw = (lr & 7) << 4;      // read-side XOR swizzle term

  f32x4 acc[4][FN];
  #pragma unroll
  for (int i = 0; i < 4; ++i)
    #pragma unroll
    for (int j = 0; j < FN; ++j)
      #pragma unroll
      for (int q = 0; q < 4; ++q) acc[i][j][q] = 0.f;

  const char* Ab = (const char*)As;
  const char* Bb = (const char*)Bs;
  const int Lw = wave * 1024 + lane * 16;

  for (int k0 = 0; k0 < K; k0 += 64) {
    // stage A tile (128 x 64 bf16), linear LDS dest + inverse-swizzled global src
    #pragma unroll
    for (int it = 0; it < AISS; ++it) {
      int L = it * 4096 + Lw;
      int row = L >> 7;
      int cb = (L & 127) ^ ((row & 7) << 4);
      const unsigned short* g = A + (size_t)(m0 + row) * lda + k0 + (cb >> 1);
      gload16(g, (void*)((char*)As + it * 4096 + wave * 1024));
    }
    // stage B tile (BN x 64 bf16)
    #pragma unroll
    for (int it = 0; it < BISS; ++it) {
      int L = it * 4096 + Lw;
      int row = L >> 7;
      int cb = (L & 127) ^ ((row & 7) << 4);
      const unsigned short* g = Bm + (size_t)(n0 + row) * ldb + k0 + (cb >> 1);
      gload16(g, (void*)((char*)Bs + it * 4096 + wave * 1024));
    }
    asm volatile("s_waitcnt vmcnt(0)" ::: "memory");
    __syncthreads();

    #pragma unroll
    for (int kk = 0; kk < 2; ++kk) {
      bf16x8 a[4], bfr[FN];
      const int cbase = (kk << 6) + (lg << 4);
      #pragma unroll
      for (int mi = 0; mi < 4; ++mi) {
        int r = wm + mi * 16 + lr;
        a[mi] = *(const bf16x8*)(Ab + (r << 7) + (cbase ^ sw));
      }
      #pragma unroll
      for (int ni = 0; ni < FN; ++ni) {
        int r = wn + ni * 16 + lr;
        bfr[ni] = *(const bf16x8*)(Bb + (r << 7) + (cbase ^ sw));
      }
      #pragma unroll
      for (int mi = 0; mi < 4; ++mi)
        #pragma unroll
        for (int ni = 0; ni < FN; ++ni)
          acc[mi][ni] = __builtin_amdgcn_mfma_f32_16x16x32_bf16(a[mi], bfr[ni], acc[mi][ni], 0, 0, 0);
    }
    __syncthreads();
  }

  // epilogue: D frag lane mapping col = lane&15, row = (lane>>4)*4 + r
  #pragma unroll
  for (int mi = 0; mi < 4; ++mi) {
    #pragma unroll
    for (int ni = 0; ni < FN; ++ni) {
      int gn = n0 + wn + ni * 16 + lr;
      #pragma unroll
      for (int r = 0; r < 4; ++r) {
        int gm = m0 + wm + mi * 16 + lg * 4 + r;
        float v = acc[mi][ni][r];
        if (EPI == 0) {
          v += bias[gn];
          v = gelu_exact(v);
          v *= wcol[(size_t)gm * 8];
          Ch[(size_t)gm * ldh + gn] = f2bf(v);
        } else if (EPI == 1) {
          Cf[(size_t)gm * ldc + gn] += v;
        } else {
          if (gn < nvalid) Cf[(size_t)gm * ldc + gn] = v + bias[gn];
        }
      }
    }
  }
}

// ---------------- launch ----------------
extern "C" void kernel_launch(void* const* d_in, const int* in_sizes, int n_in,
                              void* d_out, int out_size, void* d_ws, size_t ws_size,
                              hipStream_t stream) {
  const float* x      = (const float*)d_in[0];
  const float* sig    = (const float*)d_in[1];
  const float* W_up   = (const float*)d_in[2];
  const float* b_up   = (const float*)d_in[3];
  const float* W_down = (const float*)d_in[4];
  const float* b_down = (const float*)d_in[5];
  const float* W_cls  = (const float*)d_in[6];
  const float* b_cls  = (const float*)d_in[7];

  float* outp   = (float*)d_out;
  float* logits  = outp;                       // 4096*1000
  float* idx_out = outp + 4096000;             // 4096 (as float)
  float* w_out   = outp + 4096000 + 4096;      // 4096*8

  char* ws = (char*)d_ws;
  unsigned short* xb    = (unsigned short*)ws;  ws += 8388608;    // 4096x1024 bf16
  unsigned short* hsc   = (unsigned short*)ws;  ws += 33554432;   // 4096x4096 bf16
  unsigned short* Bbuf  = (unsigned short*)ws;  ws += 8388608;    // per-tile weights bf16
  unsigned short* outb  = (unsigned short*)ws;  ws += 8388608;    // 4096x1024 bf16
  unsigned short* wclsb = (unsigned short*)ws;  ws += 2097152;    // 1024x1024 bf16 (padded)
  float* out_f          = (float*)ws;           ws += 16777216;   // 4096x1024 f32
  float* w_ws           = (float*)ws;           ws += 131072;     // 4096x8 f32

  dim3 blk(256);

  conv_bf16<<<dim3(4096), blk, 0, stream>>>(x, xb, 1048576);
  score_init<<<dim3(4096), blk, 0, stream>>>(x, sig, b_down, w_ws, out_f, w_out, idx_out);
  conv_wcls<<<dim3(1024), blk, 0, stream>>>(W_cls, wclsb);

  for (int t = 0; t < 8; ++t) {
    // up: h_sc = bf16( w_t * gelu(x @ W_up[t]^T + b_up[t]) )
    conv_bf16<<<dim3(4096), blk, 0, stream>>>(W_up + (size_t)t * 4194304, Bbuf, 1048576);
    gemm_k<128, 0><<<dim3(32, 32), blk, 0, stream>>>(
        xb, 1024, Bbuf, 1024, 1024,
        (float*)nullptr, 0, 0, hsc, 4096, b_up + t * 4096, w_ws + t);
    // down: out_f += h_sc @ W_down[t]^T
    conv_bf16<<<dim3(4096), blk, 0, stream>>>(W_down + (size_t)t * 4194304, Bbuf, 1048576);
    gemm_k<64, 1><<<dim3(16, 32), blk, 0, stream>>>(
        hsc, 4096, Bbuf, 4096, 4096,
        out_f, 1024, 0, (unsigned short*)nullptr, 0, (const float*)nullptr, (const float*)nullptr);
  }

  conv_bf16<<<dim3(4096), blk, 0, stream>>>(out_f, outb, 1048576);
  gemm_k<64, 2><<<dim3(16, 32), blk, 0, stream>>>(
      outb, 1024, wclsb, 1024, 1024,
      logits, 1000, 1000, (unsigned short*)nullptr, 0, b_cls, (const float*)nullptr);
}

// Round 2
// 834.718 us; speedup vs baseline: 1.2122x; 1.2122x over previous
//
#include <hip/hip_runtime.h>
#include <stdint.h>

// SimpleTrixFFN round 2: concatenated GEMMs.
//  up:   h_sc(4096,32768) = w_t * gelu(x @ W_up_cat^T + b_up)    [one GEMM, N=32768]
//  down: out = out_init + h_sc @ W_dn_cat^T                      [one GEMM, K=32768, split-K=4]
//  cls:  logits = outb @ W_cls^T + b_cls
// fp32 routing (exact argmax), bf16 MFMA 16x16x32, tanh-form gelu (|err|<=2e-4).

typedef __attribute__((ext_vector_type(8))) __bf16 bf16x8;
typedef __attribute__((ext_vector_type(4))) float f32x4;

__device__ __forceinline__ unsigned short f2bf(float f) {
  union { float f; unsigned int u; } c; c.f = f;
  unsigned int u = c.u;
  u += 0x7FFFu + ((u >> 16) & 1u);   // round-to-nearest-even
  return (unsigned short)(u >> 16);
}

__device__ __forceinline__ float gelu_fast(float x) {
  // x * sigmoid(1.5957691 * (x + 0.044715 x^3)) == tanh-form gelu, |err| <= ~2e-4
  float x2 = x * x;
  float p = __builtin_fmaf(0.044715f * x2, x, x);
  float e = __expf(-1.5957691216057308f * p);
  return x / (1.0f + e);
}

__device__ __forceinline__ void gload16(const void* g, void* l) {
  __builtin_amdgcn_global_load_lds((const __attribute__((address_space(1))) void*)g,
                                   (__attribute__((address_space(3))) void*)l,
                                   16, 0, 0);
}

// ---------------- conversion kernels ----------------
__global__ void conv_bf16(const float* __restrict__ in, unsigned short* __restrict__ out, int n4) {
  int i = blockIdx.x * blockDim.x + threadIdx.x;
  if (i >= n4) return;
  float4 v = reinterpret_cast<const float4*>(in)[i];
  ushort4 o;
  o.x = f2bf(v.x); o.y = f2bf(v.y); o.z = f2bf(v.z); o.w = f2bf(v.w);
  reinterpret_cast<ushort4*>(out)[i] = o;
}

// W_down (8,1024,4096)[t][d][h] -> bf16 (1024, 32768)[d][t*4096+h]
__global__ void conv_wdn(const float* __restrict__ in, unsigned short* __restrict__ out) {
  int i = blockIdx.x * blockDim.x + threadIdx.x;   // 8388608 threads
  int idx = i * 4;
  int h = idx & 4095;
  int d = (idx >> 12) & 1023;
  int t = idx >> 22;
  float4 v = *reinterpret_cast<const float4*>(in + (size_t)(t * 1024 + d) * 4096 + h);
  ushort4 o;
  o.x = f2bf(v.x); o.y = f2bf(v.y); o.z = f2bf(v.z); o.w = f2bf(v.w);
  *reinterpret_cast<ushort4*>(out + (size_t)d * 32768 + t * 4096 + h) = o;
}

// W_cls (1000,1024) -> padded bf16 (1024,1024), zero rows 1000..1023
__global__ void conv_wcls(const float* __restrict__ in, unsigned short* __restrict__ out) {
  int i = blockIdx.x * blockDim.x + threadIdx.x;
  int idx = i * 4;
  int row = idx >> 10;
  float4 v = make_float4(0.f, 0.f, 0.f, 0.f);
  if (row < 1000) v = *reinterpret_cast<const float4*>(in + row * 1024 + (idx & 1023));
  ushort4 o;
  o.x = f2bf(v.x); o.y = f2bf(v.y); o.z = f2bf(v.z); o.w = f2bf(v.w);
  reinterpret_cast<ushort4*>(out)[i] = o;
}

// ---------------- routing: scores, softmax, argmax, out-init ----------------
__global__ void score_init(const float* __restrict__ x, const float* __restrict__ sig,
                           const float* __restrict__ b_down,
                           float* __restrict__ w_ws, float* __restrict__ out_init,
                           float* __restrict__ w_out, float* __restrict__ idx_out) {
  const int b = blockIdx.x;
  const int tid = threadIdx.x;
  const int lane = tid & 63;
  const int wave = tid >> 6;
  const float* xr = x + (size_t)b * 1024;

  float p[8];
  #pragma unroll
  for (int t = 0; t < 8; ++t) p[t] = 0.f;

  for (int k = tid; k < 1024; k += 256) {
    float xv = xr[k];
    #pragma unroll
    for (int t = 0; t < 8; ++t) p[t] += xv * sig[t * 1024 + k];
  }
  #pragma unroll
  for (int t = 0; t < 8; ++t) {
    #pragma unroll
    for (int off = 32; off > 0; off >>= 1) p[t] += __shfl_down(p[t], off);
  }
  __shared__ float red[4][8];
  __shared__ float wsh[8];
  if (lane == 0) {
    #pragma unroll
    for (int t = 0; t < 8; ++t) red[wave][t] = p[t];
  }
  __syncthreads();
  if (tid == 0) {
    float s[8];
    #pragma unroll
    for (int t = 0; t < 8; ++t) s[t] = red[0][t] + red[1][t] + red[2][t] + red[3][t];
    int amax = 0; float mx = s[0];
    #pragma unroll
    for (int t = 1; t < 8; ++t) { if (s[t] > mx) { mx = s[t]; amax = t; } }
    float e[8], sum = 0.f;
    #pragma unroll
    for (int t = 0; t < 8; ++t) { e[t] = expf((s[t] - mx) * 2.0f); sum += e[t]; }
    float inv = 1.0f / sum;
    #pragma unroll
    for (int t = 0; t < 8; ++t) {
      float wv = e[t] * inv;
      wsh[t] = wv;
      w_out[(size_t)b * 8 + t] = wv;
      w_ws[(size_t)b * 8 + t] = wv;
    }
    idx_out[b] = (float)amax;
  }
  __syncthreads();
  for (int d = tid; d < 1024; d += 256) {
    float acc = xr[d];
    #pragma unroll
    for (int t = 0; t < 8; ++t) acc += wsh[t] * b_down[t * 1024 + d];
    out_init[(size_t)b * 1024 + d] = acc;
  }
}

// ---------------- GEMM: C[m][n] = sum_k A[m][k]*B[n][k], bf16 row-major ----------------
// BM=128, BK=64. EPI: 0 = up (gelu*w -> bf16 Ch), 2 = cls (Cf = v + bias, guard n),
//                 3 = split-K partial (Cf[z] = v; A,B offset by z*K)
template <int BN, int EPI>
__global__ __launch_bounds__(256, 2) void gemm_k(
    const unsigned short* __restrict__ A, int lda,
    const unsigned short* __restrict__ Bm, int ldb,
    int K,
    float* __restrict__ Cf, int ldc, int nvalid,
    unsigned short* __restrict__ Ch, int ldh,
    const float* __restrict__ bias,
    const float* __restrict__ wcol) {
  constexpr int FN = BN / 32;
  constexpr int AISS = 4;
  constexpr int BISS = BN / 32;

  __shared__ unsigned short As[128 * 64];
  __shared__ unsigned short Bs[BN * 64];

  if (EPI == 3) {
    size_t kz = (size_t)blockIdx.z * K;
    A += kz;
    Bm += kz;
    Cf += (size_t)blockIdx.z * 4194304;   // 4096*1024 per partial
  }

  const int tid  = threadIdx.x;
  const int lane = tid & 63;
  const int wave = tid >> 6;
  const int m0 = blockIdx.y * 128;
  const int n0 = blockIdx.x * BN;
  const int lr = lane & 15;
  const int lg = lane >> 4;
  const int wm = (wave >> 1) * 64;
  const int wn = (wave & 1) * (BN / 2);
  const int sw = (lr & 7) << 4;

  f32x4 acc[4][FN];
  #pragma unroll
  for (int i = 0; i < 4; ++i)
    #pragma unroll
    for (int j = 0; j < FN; ++j)
      #pragma unroll
      for (int q = 0; q < 4; ++q) acc[i][j][q] = 0.f;

  const char* Ab = (const char*)As;
  const char* Bb = (const char*)Bs;
  const int Lw = wave * 1024 + lane * 16;

  for (int k0 = 0; k0 < K; k0 += 64) {
    #pragma unroll
    for (int it = 0; it < AISS; ++it) {
      int L = it * 4096 + Lw;
      int row = L >> 7;
      int cb = (L & 127) ^ ((row & 7) << 4);
      const unsigned short* g = A + (size_t)(m0 + row) * lda + k0 + (cb >> 1);
      gload16(g, (void*)((char*)As + it * 4096 + wave * 1024));
    }
    #pragma unroll
    for (int it = 0; it < BISS; ++it) {
      int L = it * 4096 + Lw;
      int row = L >> 7;
      int cb = (L & 127) ^ ((row & 7) << 4);
      const unsigned short* g = Bm + (size_t)(n0 + row) * ldb + k0 + (cb >> 1);
      gload16(g, (void*)((char*)Bs + it * 4096 + wave * 1024));
    }
    asm volatile("s_waitcnt vmcnt(0)" ::: "memory");
    __syncthreads();

    #pragma unroll
    for (int kk = 0; kk < 2; ++kk) {
      bf16x8 a[4], bfr[FN];
      const int cbase = (kk << 6) + (lg << 4);
      #pragma unroll
      for (int mi = 0; mi < 4; ++mi) {
        int r = wm + mi * 16 + lr;
        a[mi] = *(const bf16x8*)(Ab + (r << 7) + (cbase ^ sw));
      }
      #pragma unroll
      for (int ni = 0; ni < FN; ++ni) {
        int r = wn + ni * 16 + lr;
        bfr[ni] = *(const bf16x8*)(Bb + (r << 7) + (cbase ^ sw));
      }
      #pragma unroll
      for (int mi = 0; mi < 4; ++mi)
        #pragma unroll
        for (int ni = 0; ni < FN; ++ni)
          acc[mi][ni] = __builtin_amdgcn_mfma_f32_16x16x32_bf16(a[mi], bfr[ni], acc[mi][ni], 0, 0, 0);
    }
    __syncthreads();
  }

  // D frag mapping: col = lane&15, row = (lane>>4)*4 + r
  const int tblk = n0 >> 12;   // tile index (big up path: block n-span 128 never crosses 4096)
  #pragma unroll
  for (int mi = 0; mi < 4; ++mi) {
    float wrow[4];
    if (EPI == 0) {
      #pragma unroll
      for (int r = 0; r < 4; ++r)
        wrow[r] = wcol[(size_t)(m0 + wm + mi * 16 + lg * 4 + r) * 8 + tblk];
    }
    #pragma unroll
    for (int ni = 0; ni < FN; ++ni) {
      int gn = n0 + wn + ni * 16 + lr;
      #pragma unroll
      for (int r = 0; r < 4; ++r) {
        int gm = m0 + wm + mi * 16 + lg * 4 + r;
        float v = acc[mi][ni][r];
        if (EPI == 0) {
          v += bias[gn];
          v = gelu_fast(v);
          v *= wrow[r];
          Ch[(size_t)gm * ldh + gn] = f2bf(v);
        } else if (EPI == 3) {
          Cf[(size_t)gm * ldc + gn] = v;
        } else {
          if (gn < nvalid) Cf[(size_t)gm * ldc + gn] = v + bias[gn];
        }
      }
    }
  }
}

// outb = bf16(out_init + p0+p1+p2+p3)
__global__ void combine_k(const float* __restrict__ init, const float* __restrict__ parts,
                          unsigned short* __restrict__ out) {
  int i = blockIdx.x * blockDim.x + threadIdx.x;   // 1048576 threads
  float4 s = reinterpret_cast<const float4*>(init)[i];
  #pragma unroll
  for (int z = 0; z < 4; ++z) {
    float4 p = reinterpret_cast<const float4*>(parts + (size_t)z * 4194304)[i];
    s.x += p.x; s.y += p.y; s.z += p.z; s.w += p.w;
  }
  ushort4 o;
  o.x = f2bf(s.x); o.y = f2bf(s.y); o.z = f2bf(s.z); o.w = f2bf(s.w);
  reinterpret_cast<ushort4*>(out)[i] = o;
}

// ---------------- launch ----------------
extern "C" void kernel_launch(void* const* d_in, const int* in_sizes, int n_in,
                              void* d_out, int out_size, void* d_ws, size_t ws_size,
                              hipStream_t stream) {
  const float* x      = (const float*)d_in[0];
  const float* sig    = (const float*)d_in[1];
  const float* W_up   = (const float*)d_in[2];
  const float* b_up   = (const float*)d_in[3];
  const float* W_down = (const float*)d_in[4];
  const float* b_down = (const float*)d_in[5];
  const float* W_cls  = (const float*)d_in[6];
  const float* b_cls  = (const float*)d_in[7];

  float* outp    = (float*)d_out;
  float* logits  = outp;                       // 4096*1000
  float* idx_out = outp + 4096000;             // 4096
  float* w_out   = outp + 4096000 + 4096;      // 4096*8

  char* ws = (char*)d_ws;
  unsigned short* xb    = (unsigned short*)ws;  ws += 8388608;    // x bf16 (4096,1024)
  unsigned short* hsc   = (unsigned short*)ws;  ws += 268435456;  // h_sc bf16 (4096,32768)
  unsigned short* wupb  = (unsigned short*)ws;  ws += 67108864;   // W_up bf16 (32768,1024)
  unsigned short* wdnb  = (unsigned short*)ws;  ws += 67108864;   // W_dn bf16 (1024,32768)
  unsigned short* wclsb = (unsigned short*)ws;  ws += 2097152;    // W_cls bf16 padded (1024,1024)
  unsigned short* outb  = (unsigned short*)ws;  ws += 8388608;    // out bf16 (4096,1024)
  float* out_init       = (float*)ws;           ws += 16777216;   // x + sum_t w_t b_down (f32)
  float* parts          = (float*)ws;           ws += 67108864;   // 4x split-K partials (f32)
  float* w_ws           = (float*)ws;           ws += 131072;     // weights (4096,8) f32

  dim3 blk(256);

  conv_bf16<<<dim3(4096), blk, 0, stream>>>(x, xb, 1048576);
  score_init<<<dim3(4096), blk, 0, stream>>>(x, sig, b_down, w_ws, out_init, w_out, idx_out);
  conv_bf16<<<dim3(32768), blk, 0, stream>>>(W_up, wupb, 8388608);
  conv_wdn<<<dim3(32768), blk, 0, stream>>>(W_down, wdnb);
  conv_wcls<<<dim3(1024), blk, 0, stream>>>(W_cls, wclsb);

  // up: h_sc = bf16( w * gelu(x @ Wup^T + b_up) ), M=4096 N=32768 K=1024
  gemm_k<128, 0><<<dim3(256, 32), blk, 0, stream>>>(
      xb, 1024, wupb, 1024, 1024,
      (float*)nullptr, 0, 0, hsc, 32768, b_up, w_ws);

  // down: parts[z] = h_sc @ Wdn^T over K-chunk z, M=4096 N=1024 K=32768 split 4
  gemm_k<128, 3><<<dim3(8, 32, 4), blk, 0, stream>>>(
      hsc, 32768, wdnb, 32768, 8192,
      parts, 1024, 0, (unsigned short*)nullptr, 0, (const float*)nullptr, (const float*)nullptr);

  combine_k<<<dim3(4096), blk, 0, stream>>>(out_init, parts, outb);

  // cls: logits = outb @ Wcls^T + b_cls, M=4096 N=1024(pad) K=1024
  gemm_k<64, 2><<<dim3(16, 32), blk, 0, stream>>>(
      outb, 1024, wclsb, 1024, 1024,
      logits, 1000, 1000, (unsigned short*)nullptr, 0, b_cls, (const float*)nullptr);
}

// Round 3
// 787.055 us; speedup vs baseline: 1.2856x; 1.0606x over previous
//
#include <hip/hip_runtime.h>
#include <stdint.h>

// SimpleTrixFFN round 3: 256x256-tile 8-wave ring-pipelined GEMMs (T2+T3+T4+T5),
// counted vmcnt(8) steady state, 4-deep 32-k LDS ring, XCD-chunked block swizzle.

typedef __attribute__((ext_vector_type(8))) __bf16 bf16x8;
typedef __attribute__((ext_vector_type(4))) float f32x4;

__device__ __forceinline__ unsigned short f2bf(float f) {
  union { float f; unsigned int u; } c; c.f = f;
  unsigned int u = c.u;
  u += 0x7FFFu + ((u >> 16) & 1u);
  return (unsigned short)(u >> 16);
}

__device__ __forceinline__ float gelu_fast(float x) {
  float x2 = x * x;
  float p = __builtin_fmaf(0.044715f * x2, x, x);
  float e = __expf(-1.5957691216057308f * p);
  return x / (1.0f + e);
}

__device__ __forceinline__ void gload16(const void* g, void* l) {
  __builtin_amdgcn_global_load_lds((const __attribute__((address_space(1))) void*)g,
                                   (__attribute__((address_space(3))) void*)l,
                                   16, 0, 0);
}

// ---------------- conversion kernels ----------------
__global__ void conv_bf16(const float* __restrict__ in, unsigned short* __restrict__ out, int n4) {
  int i = blockIdx.x * blockDim.x + threadIdx.x;
  if (i >= n4) return;
  float4 v = reinterpret_cast<const float4*>(in)[i];
  ushort4 o;
  o.x = f2bf(v.x); o.y = f2bf(v.y); o.z = f2bf(v.z); o.w = f2bf(v.w);
  reinterpret_cast<ushort4*>(out)[i] = o;
}

__global__ void conv_wdn(const float* __restrict__ in, unsigned short* __restrict__ out) {
  int i = blockIdx.x * blockDim.x + threadIdx.x;
  int idx = i * 4;
  int h = idx & 4095;
  int d = (idx >> 12) & 1023;
  int t = idx >> 22;
  float4 v = *reinterpret_cast<const float4*>(in + (size_t)(t * 1024 + d) * 4096 + h);
  ushort4 o;
  o.x = f2bf(v.x); o.y = f2bf(v.y); o.z = f2bf(v.z); o.w = f2bf(v.w);
  *reinterpret_cast<ushort4*>(out + (size_t)d * 32768 + t * 4096 + h) = o;
}

__global__ void conv_wcls(const float* __restrict__ in, unsigned short* __restrict__ out) {
  int i = blockIdx.x * blockDim.x + threadIdx.x;
  int idx = i * 4;
  int row = idx >> 10;
  float4 v = make_float4(0.f, 0.f, 0.f, 0.f);
  if (row < 1000) v = *reinterpret_cast<const float4*>(in + row * 1024 + (idx & 1023));
  ushort4 o;
  o.x = f2bf(v.x); o.y = f2bf(v.y); o.z = f2bf(v.z); o.w = f2bf(v.w);
  reinterpret_cast<ushort4*>(out)[i] = o;
}

// ---------------- routing ----------------
__global__ void score_init(const float* __restrict__ x, const float* __restrict__ sig,
                           const float* __restrict__ b_down,
                           float* __restrict__ w_ws, float* __restrict__ out_init,
                           float* __restrict__ w_out, float* __restrict__ idx_out) {
  const int b = blockIdx.x;
  const int tid = threadIdx.x;
  const int lane = tid & 63;
  const int wave = tid >> 6;
  const float* xr = x + (size_t)b * 1024;

  float p[8];
  #pragma unroll
  for (int t = 0; t < 8; ++t) p[t] = 0.f;
  for (int k = tid; k < 1024; k += 256) {
    float xv = xr[k];
    #pragma unroll
    for (int t = 0; t < 8; ++t) p[t] += xv * sig[t * 1024 + k];
  }
  #pragma unroll
  for (int t = 0; t < 8; ++t) {
    #pragma unroll
    for (int off = 32; off > 0; off >>= 1) p[t] += __shfl_down(p[t], off);
  }
  __shared__ float red[4][8];
  __shared__ float wsh[8];
  if (lane == 0) {
    #pragma unroll
    for (int t = 0; t < 8; ++t) red[wave][t] = p[t];
  }
  __syncthreads();
  if (tid == 0) {
    float s[8];
    #pragma unroll
    for (int t = 0; t < 8; ++t) s[t] = red[0][t] + red[1][t] + red[2][t] + red[3][t];
    int amax = 0; float mx = s[0];
    #pragma unroll
    for (int t = 1; t < 8; ++t) { if (s[t] > mx) { mx = s[t]; amax = t; } }
    float e[8], sum = 0.f;
    #pragma unroll
    for (int t = 0; t < 8; ++t) { e[t] = expf((s[t] - mx) * 2.0f); sum += e[t]; }
    float inv = 1.0f / sum;
    #pragma unroll
    for (int t = 0; t < 8; ++t) {
      float wv = e[t] * inv;
      wsh[t] = wv;
      w_out[(size_t)b * 8 + t] = wv;
      w_ws[(size_t)b * 8 + t] = wv;
    }
    idx_out[b] = (float)amax;
  }
  __syncthreads();
  for (int d = tid; d < 1024; d += 256) {
    float acc = xr[d];
    #pragma unroll
    for (int t = 0; t < 8; ++t) acc += wsh[t] * b_down[t * 1024 + d];
    out_init[(size_t)b * 1024 + d] = acc;
  }
}

// ---------------- pipelined 256x256 GEMM ----------------
// C[m][n] = sum_k A[m][k]*B[n][k], A/B bf16 row-major.
// MODE 0: up (M=4096,N=32768,K=1024): Ch = bf16(wcol * gelu(v + bias))
// MODE 1: down split-K (M=4096,N=1024,K=8192/z, z=4): Cf[z] = v
template <int MODE>
__global__ __launch_bounds__(512, 2) void gemm8(
    const unsigned short* __restrict__ A, int lda,
    const unsigned short* __restrict__ Bm, int ldb,
    float* __restrict__ Cf,
    unsigned short* __restrict__ Ch,
    const float* __restrict__ bias,
    const float* __restrict__ wcol) {
  constexpr int NU = (MODE == 0) ? 32 : 256;   // K/32
  __shared__ char lds[131072];                 // A ring 4x16KB @0, B ring 4x16KB @64K

  const int tid = threadIdx.x;
  const int f = blockIdx.x;
  int m0, n0;
  size_t koff = 0;
  if (MODE == 0) {
    int sf = (f & 7) * 256 + (f >> 3);         // 2048 blocks, 256/XCD chunk
    n0 = (sf >> 4) * 256;
    m0 = (sf & 15) * 256;
  } else {
    int sf = (f & 7) * 32 + (f >> 3);          // 256 blocks, 32/XCD chunk
    int z = sf >> 6, rem = sf & 63;
    m0 = (rem >> 2) * 256;
    n0 = (rem & 3) * 256;
    koff = (size_t)z * 8192;
    Cf += (size_t)z * 4194304;
  }

  // staging constants: pass p writes LDS row p*128 + tid/4, bytes (tid&3)*16
  const int srow = tid >> 2;
  const int selem = ((tid & 3) * 8) ^ (((tid >> 3) & 3) * 8);  // inverse-swizzled k-offset
  const unsigned short* Ag = A + (size_t)(m0 + srow) * lda + koff + selem;
  const unsigned short* Bg = Bm + (size_t)(n0 + srow) * ldb + koff + selem;
  const size_t ldaB = (size_t)128 * lda, ldbB = (size_t)128 * ldb;
  char* ldsA = lds + tid * 16;
  char* ldsB = lds + 65536 + tid * 16;

  const int lane = tid & 63;
  const int wave = tid >> 6;
  const int lr = lane & 15, lg = lane >> 4;
  const int wm = (wave >> 2) * 128;            // 2 M-waves x 4 N-waves
  const int wn = (wave & 3) * 64;

  // per-fragment LDS read offsets (row*64 + (lg*16 ^ swz(row)))
  int offA[8], offB[4];
  #pragma unroll
  for (int mi = 0; mi < 8; ++mi) {
    int r = wm + mi * 16 + lr;
    offA[mi] = r * 64 + ((lg << 4) ^ (((r >> 1) & 3) << 4));
  }
  #pragma unroll
  for (int ni = 0; ni < 4; ++ni) {
    int r = wn + ni * 16 + lr;
    offB[ni] = 65536 + r * 64 + ((lg << 4) ^ (((r >> 1) & 3) << 4));
  }

  f32x4 acc[8][4];
  #pragma unroll
  for (int i = 0; i < 8; ++i)
    #pragma unroll
    for (int j = 0; j < 4; ++j)
      #pragma unroll
      for (int q = 0; q < 4; ++q) acc[i][j][q] = 0.f;

#define STAGE(v)                                                        \
  {                                                                     \
    const int s_ = ((v) & 3) * 16384;                                   \
    const unsigned short* ga_ = Ag + (size_t)(v) * 32;                  \
    const unsigned short* gb_ = Bg + (size_t)(v) * 32;                  \
    gload16(ga_, ldsA + s_);                                            \
    gload16(ga_ + ldaB, ldsA + s_ + 8192);                              \
    gload16(gb_, ldsB + s_);                                            \
    gload16(gb_ + ldbB, ldsB + s_ + 8192);                              \
  }

#define COMPUTE(u)                                                      \
  {                                                                     \
    const int s_ = ((u) & 3) * 16384;                                   \
    bf16x8 av[8], bv[4];                                                \
    _Pragma("unroll")                                                   \
    for (int mi = 0; mi < 8; ++mi)                                      \
      av[mi] = *(const bf16x8*)(lds + s_ + offA[mi]);                   \
    _Pragma("unroll")                                                   \
    for (int ni = 0; ni < 4; ++ni)                                      \
      bv[ni] = *(const bf16x8*)(lds + s_ + offB[ni]);                   \
    __builtin_amdgcn_s_setprio(1);                                      \
    _Pragma("unroll")                                                   \
    for (int mi = 0; mi < 8; ++mi)                                      \
      _Pragma("unroll")                                                 \
      for (int ni = 0; ni < 4; ++ni)                                    \
        acc[mi][ni] = __builtin_amdgcn_mfma_f32_16x16x32_bf16(          \
            av[mi], bv[ni], acc[mi][ni], 0, 0, 0);                      \
    __builtin_amdgcn_s_setprio(0);                                      \
  }

  STAGE(0) STAGE(1) STAGE(2)

  for (int u = 0; u < NU - 2; ++u) {
    asm volatile("s_waitcnt vmcnt(8)" ::: "memory");
    __builtin_amdgcn_s_barrier();
    if (u + 3 < NU) STAGE(u + 3)
    COMPUTE(u)
  }
  asm volatile("s_waitcnt vmcnt(4)" ::: "memory");
  __builtin_amdgcn_s_barrier();
  COMPUTE(NU - 2)
  asm volatile("s_waitcnt vmcnt(0)" ::: "memory");
  __builtin_amdgcn_s_barrier();
  COMPUTE(NU - 1)

#undef STAGE
#undef COMPUTE

  // epilogue: D frag mapping col = lane&15, row = (lane>>4)*4 + r
  #pragma unroll
  for (int mi = 0; mi < 8; ++mi) {
    float wr[4];
    if (MODE == 0) {
      #pragma unroll
      for (int r = 0; r < 4; ++r)
        wr[r] = wcol[(size_t)(m0 + wm + mi * 16 + lg * 4 + r) * 8 + (n0 >> 12)];
    }
    #pragma unroll
    for (int ni = 0; ni < 4; ++ni) {
      int gn = n0 + wn + ni * 16 + lr;
      #pragma unroll
      for (int r = 0; r < 4; ++r) {
        int gm = m0 + wm + mi * 16 + lg * 4 + r;
        float v = acc[mi][ni][r];
        if (MODE == 0) {
          v += bias[gn];
          v = gelu_fast(v) * wr[r];
          Ch[(size_t)gm * 32768 + gn] = f2bf(v);
        } else {
          Cf[(size_t)gm * 1024 + gn] = v;
        }
      }
    }
  }
}

// ---------------- cls GEMM (128-tile, 2-phase; small) ----------------
template <int BN>
__global__ __launch_bounds__(256, 2) void gemm_cls(
    const unsigned short* __restrict__ A, int lda,
    const unsigned short* __restrict__ Bm, int ldb,
    int K, float* __restrict__ Cf, int ldc, int nvalid,
    const float* __restrict__ bias) {
  constexpr int FN = BN / 32;
  __shared__ unsigned short As[128 * 64];
  __shared__ unsigned short Bs[BN * 64];

  const int tid = threadIdx.x;
  const int lane = tid & 63;
  const int wave = tid >> 6;
  const int m0 = blockIdx.y * 128;
  const int n0 = blockIdx.x * BN;
  const int lr = lane & 15;
  const int lg = lane >> 4;
  const int wm = (wave >> 1) * 64;
  const int wn = (wave & 1) * (BN / 2);
  const int sw = (lr & 7) << 4;

  f32x4 acc[4][FN];
  #pragma unroll
  for (int i = 0; i < 4; ++i)
    #pragma unroll
    for (int j = 0; j < FN; ++j)
      #pragma unroll
      for (int q = 0; q < 4; ++q) acc[i][j][q] = 0.f;

  const char* Ab = (const char*)As;
  const char* Bb = (const char*)Bs;
  const int Lw = wave * 1024 + lane * 16;

  for (int k0 = 0; k0 < K; k0 += 64) {
    #pragma unroll
    for (int it = 0; it < 4; ++it) {
      int L = it * 4096 + Lw;
      int row = L >> 7;
      int cb = (L & 127) ^ ((row & 7) << 4);
      gload16(A + (size_t)(m0 + row) * lda + k0 + (cb >> 1),
              (void*)((char*)As + it * 4096 + wave * 1024));
    }
    #pragma unroll
    for (int it = 0; it < FN; ++it) {
      int L = it * 4096 + Lw;
      int row = L >> 7;
      int cb = (L & 127) ^ ((row & 7) << 4);
      gload16(Bm + (size_t)(n0 + row) * ldb + k0 + (cb >> 1),
              (void*)((char*)Bs + it * 4096 + wave * 1024));
    }
    asm volatile("s_waitcnt vmcnt(0)" ::: "memory");
    __syncthreads();

    #pragma unroll
    for (int kk = 0; kk < 2; ++kk) {
      bf16x8 a[4], bfr[FN];
      const int cbase = (kk << 6) + (lg << 4);
      #pragma unroll
      for (int mi = 0; mi < 4; ++mi)
        a[mi] = *(const bf16x8*)(Ab + ((wm + mi * 16 + lr) << 7) + (cbase ^ sw));
      #pragma unroll
      for (int ni = 0; ni < FN; ++ni)
        bfr[ni] = *(const bf16x8*)(Bb + ((wn + ni * 16 + lr) << 7) + (cbase ^ sw));
      #pragma unroll
      for (int mi = 0; mi < 4; ++mi)
        #pragma unroll
        for (int ni = 0; ni < FN; ++ni)
          acc[mi][ni] = __builtin_amdgcn_mfma_f32_16x16x32_bf16(a[mi], bfr[ni], acc[mi][ni], 0, 0, 0);
    }
    __syncthreads();
  }

  #pragma unroll
  for (int mi = 0; mi < 4; ++mi)
    #pragma unroll
    for (int ni = 0; ni < FN; ++ni) {
      int gn = n0 + wn + ni * 16 + lr;
      #pragma unroll
      for (int r = 0; r < 4; ++r) {
        int gm = m0 + wm + mi * 16 + lg * 4 + r;
        if (gn < nvalid) Cf[(size_t)gm * ldc + gn] = acc[mi][ni][r] + bias[gn];
      }
    }
}

// outb = bf16(out_init + p0+p1+p2+p3)
__global__ void combine_k(const float* __restrict__ init, const float* __restrict__ parts,
                          unsigned short* __restrict__ out) {
  int i = blockIdx.x * blockDim.x + threadIdx.x;
  float4 s = reinterpret_cast<const float4*>(init)[i];
  #pragma unroll
  for (int z = 0; z < 4; ++z) {
    float4 p = reinterpret_cast<const float4*>(parts + (size_t)z * 4194304)[i];
    s.x += p.x; s.y += p.y; s.z += p.z; s.w += p.w;
  }
  ushort4 o;
  o.x = f2bf(s.x); o.y = f2bf(s.y); o.z = f2bf(s.z); o.w = f2bf(s.w);
  reinterpret_cast<ushort4*>(out)[i] = o;
}

// ---------------- launch ----------------
extern "C" void kernel_launch(void* const* d_in, const int* in_sizes, int n_in,
                              void* d_out, int out_size, void* d_ws, size_t ws_size,
                              hipStream_t stream) {
  const float* x      = (const float*)d_in[0];
  const float* sig    = (const float*)d_in[1];
  const float* W_up   = (const float*)d_in[2];
  const float* b_up   = (const float*)d_in[3];
  const float* W_down = (const float*)d_in[4];
  const float* b_down = (const float*)d_in[5];
  const float* W_cls  = (const float*)d_in[6];
  const float* b_cls  = (const float*)d_in[7];

  float* outp    = (float*)d_out;
  float* logits  = outp;
  float* idx_out = outp + 4096000;
  float* w_out   = outp + 4096000 + 4096;

  char* ws = (char*)d_ws;
  unsigned short* xb    = (unsigned short*)ws;  ws += 8388608;
  unsigned short* hsc   = (unsigned short*)ws;  ws += 268435456;
  unsigned short* wupb  = (unsigned short*)ws;  ws += 67108864;
  unsigned short* wdnb  = (unsigned short*)ws;  ws += 67108864;
  unsigned short* wclsb = (unsigned short*)ws;  ws += 2097152;
  unsigned short* outb  = (unsigned short*)ws;  ws += 8388608;
  float* out_init       = (float*)ws;           ws += 16777216;
  float* parts          = (float*)ws;           ws += 67108864;
  float* w_ws           = (float*)ws;           ws += 131072;

  dim3 blk(256);

  conv_bf16<<<dim3(4096), blk, 0, stream>>>(x, xb, 1048576);
  score_init<<<dim3(4096), blk, 0, stream>>>(x, sig, b_down, w_ws, out_init, w_out, idx_out);
  conv_bf16<<<dim3(32768), blk, 0, stream>>>(W_up, wupb, 8388608);
  conv_wdn<<<dim3(32768), blk, 0, stream>>>(W_down, wdnb);
  conv_wcls<<<dim3(1024), blk, 0, stream>>>(W_cls, wclsb);

  // up: h_sc = bf16( w * gelu(x @ Wup^T + b_up) ), M=4096 N=32768 K=1024
  gemm8<0><<<dim3(2048), dim3(512), 0, stream>>>(
      xb, 1024, wupb, 1024, (float*)nullptr, hsc, b_up, w_ws);

  // down: parts[z] = h_sc @ Wdn^T (K=32768 split 4)
  gemm8<1><<<dim3(256), dim3(512), 0, stream>>>(
      hsc, 32768, wdnb, 32768, parts, (unsigned short*)nullptr,
      (const float*)nullptr, (const float*)nullptr);

  combine_k<<<dim3(4096), blk, 0, stream>>>(out_init, parts, outb);

  // cls: logits = outb @ Wcls^T + b_cls
  gemm_cls<64><<<dim3(16, 32), blk, 0, stream>>>(
      outb, 1024, wclsb, 1024, 1024, logits, 1000, 1000, b_cls);
}